// Round 1
// baseline (29274.048 us; speedup 1.0000x reference)
//
#include <hip/hip_runtime.h>
#include <math.h>

// LSTM: x (64,1024,512) f32, h0 (64,512), Wx (512,2048), Wh (512,2048), b (2048)
// out: hs (64,1024,512) f32
// Strategy: one kernel per time step (kernel boundary = global sync).
// Grid: 32 j-tiles (16 h-cols each) x 8 n-tiles (8 batch rows each) = 256 blocks.
// Block: 512 threads. Each thread accumulates one A column (one of the 64
// gate-columns for the tile: 16 cols x 4 gates) for one batch row.
// h_{t-1} is read from d_out[:, t-1, :]; c lives in d_ws.

#define DD   512
#define HH   512
#define TT   1024
#define NBATCH 64
#define FH   2048   // 4*H

__global__ __launch_bounds__(512)
void lstm_step(const float* __restrict__ x,    // (64,1024,512)
               const float* __restrict__ h0,   // (64,512)
               const float* __restrict__ Wx,   // (512,2048)
               const float* __restrict__ Wh,   // (512,2048)
               const float* __restrict__ b,    // (2048,)
               float* __restrict__ out,        // (64,1024,512)
               float* __restrict__ c_state,    // (64,512) in ws
               int t)
{
    __shared__ float xh[8][1024];   // [n_local][k]: k<512 = x_t row, k>=512 = h_prev row (32 KB)
    __shared__ float As[8][64];     // A tile staged for gate phase (2 KB)

    const int jt  = blockIdx.x;     // 0..31  -> h-cols [jt*16, jt*16+16)
    const int nt  = blockIdx.y;     // 0..7   -> batch rows [nt*8, nt*8+8)
    const int j0  = jt * 16;
    const int n0  = nt * 8;
    const int tid = threadIdx.x;

    // ---- stage x_t rows and h_prev rows into LDS (float4, coalesced) ----
    // 8 rows x 128 float4 for x, same for h.
    for (int i = tid; i < 8 * 128; i += 512) {
        int n = i >> 7;
        int q = i & 127;
        const float4* src = (const float4*)(x + ((size_t)(n0 + n) * TT + t) * DD) + q;
        ((float4*)&xh[n][0])[q] = *src;
    }
    for (int i = tid; i < 8 * 128; i += 512) {
        int n = i >> 7;
        int q = i & 127;
        const float4* src;
        if (t == 0) src = (const float4*)(h0 + (size_t)(n0 + n) * HH) + q;
        else        src = (const float4*)(out + ((size_t)(n0 + n) * TT + (t - 1)) * HH) + q;
        ((float4*)&xh[n][512])[q] = *src;
    }
    __syncthreads();

    // ---- accumulate one A column per thread ----
    const int cl  = tid & 63;       // local A-column 0..63
    const int n   = tid >> 6;       // local batch row 0..7
    const int grp = cl >> 4;        // gate: 0=i, 1=f, 2=o, 3=g
    const int jj  = cl & 15;
    const int col = grp * HH + j0 + jj;   // global column in [0,2048)

    float acc = b[col];

    const float* __restrict__ wxc = Wx + col;
    const float* __restrict__ whc = Wh + col;
    const float* __restrict__ xr  = &xh[n][0];

    #pragma unroll 8
    for (int k = 0; k < 512; ++k) {
        acc = fmaf(xr[k], wxc[(size_t)k * FH], acc);
    }
    #pragma unroll 8
    for (int k = 0; k < 512; ++k) {
        acc = fmaf(xr[512 + k], whc[(size_t)k * FH], acc);
    }

    As[n][cl] = acc;
    __syncthreads();

    // ---- gate phase: 128 cells per block (8 rows x 16 cols) ----
    if (tid < 128) {
        int nn = tid >> 4;          // 0..7
        int q  = tid & 15;          // 0..15
        float Ai = As[nn][q];
        float Af = As[nn][16 + q];
        float Ao = As[nn][32 + q];
        float Ag = As[nn][48 + q];

        int gn = n0 + nn;
        int gj = j0 + q;

        float c_old = (t == 0) ? 0.0f : c_state[gn * HH + gj];

        float ig = 1.0f / (1.0f + __expf(-Ai));
        float fg = 1.0f / (1.0f + __expf(-Af));
        float og = 1.0f / (1.0f + __expf(-Ao));
        float gg = tanhf(Ag);

        float cn = fg * c_old + ig * gg;
        float hn = og * tanhf(cn);

        c_state[gn * HH + gj] = cn;
        out[((size_t)gn * TT + t) * HH + gj] = hn;
    }
}

extern "C" void kernel_launch(void* const* d_in, const int* in_sizes, int n_in,
                              void* d_out, int out_size, void* d_ws, size_t ws_size,
                              hipStream_t stream)
{
    const float* x  = (const float*)d_in[0];
    const float* h0 = (const float*)d_in[1];
    const float* Wx = (const float*)d_in[2];
    const float* Wh = (const float*)d_in[3];
    const float* b  = (const float*)d_in[4];
    float* out     = (float*)d_out;
    float* c_state = (float*)d_ws;   // 64*512*4 = 128 KB

    dim3 grid(32, 8);
    for (int t = 0; t < TT; ++t) {
        lstm_step<<<grid, 512, 0, stream>>>(x, h0, Wx, Wh, b, out, c_state, t);
    }
}

// Round 2
// 18380.516 us; speedup vs baseline: 1.5927x; 1.5927x over previous
//
#include <hip/hip_runtime.h>
#include <math.h>

// LSTM: x (64,1024,512) f32, h0 (64,512), Wx (512,2048), Wh (512,2048), b (2048)
// out: hs (64,1024,512) f32
// One kernel per time step. Grid (32 j-tiles, 8 n-tiles) = 256 blocks, 1024 thr.
// Per block: A-tile = 8 batch rows x 64 cols (4 gates x 16 j).
// 8-way K-split, 4-col register tile per thread (float4 W loads).
// h_{t-1} read from out[:, t-1, :]; c lives in d_ws (double use ok, per-cell owner).

#define TT   1024
#define HH   512
#define FH   2048

__global__ __launch_bounds__(1024)
void lstm_step(const float* __restrict__ x,
               const float* __restrict__ h0,
               const float* __restrict__ Wx,
               const float* __restrict__ Wh,
               const float* __restrict__ b,
               float* __restrict__ out,
               float* __restrict__ c_state,
               int t)
{
    __shared__ float xh[8][1028];      // [n][k] padded (+4) to spread banks
    __shared__ float part[8][8][64];   // [kh][n][cl] partial sums (16 KB)
    __shared__ float As[8][64];        // reduced A tile

    const int jt  = blockIdx.x;        // 0..31 -> j-cols [jt*16, jt*16+16)
    const int nt  = blockIdx.y;        // 0..7  -> batch rows [nt*8, nt*8+8)
    const int j0  = jt * 16;
    const int n0  = nt * 8;
    const int tid = threadIdx.x;

    // ---- stage x_t (8x512) and h_prev (8x512) into LDS, 1 float4/thread each ----
    {
        int n = tid >> 7;              // 0..7
        int q = tid & 127;             // 0..127 float4 slots
        const float4* sx = (const float4*)(x + ((size_t)(n0 + n) * TT + t) * 512) + q;
        *(float4*)&xh[n][q * 4] = *sx;
        const float4* sh;
        if (t == 0) sh = (const float4*)(h0 + (size_t)(n0 + n) * HH) + q;
        else        sh = (const float4*)(out + ((size_t)(n0 + n) * TT + (t - 1)) * HH) + q;
        *(float4*)&xh[n][512 + q * 4] = *sh;
    }
    __syncthreads();

    // ---- GEMM: thread = (c4 0..15, n 0..7, kh 0..7) ----
    const int c4   = tid & 15;         // column quad: gate*4 + quad
    const int n    = (tid >> 4) & 7;   // local batch row
    const int kh   = tid >> 7;         // K-split index
    const int gate = c4 >> 2;
    const int quad = c4 & 3;
    const int col  = gate * HH + j0 + quad * 4;   // first of 4 consecutive cols

    const float* __restrict__ Wp =
        (kh < 4 ? Wx + (size_t)(kh * 128) * FH
                : Wh + (size_t)((kh - 4) * 128) * FH) + col;
    const float* __restrict__ xr = &xh[n][kh * 128];

    float a0 = 0.f, a1 = 0.f, a2 = 0.f, a3 = 0.f;
    #pragma unroll 4
    for (int i = 0; i < 128; ++i) {
        float4 w = *(const float4*)Wp;
        Wp += FH;
        float xv = xr[i];
        a0 = fmaf(w.x, xv, a0);
        a1 = fmaf(w.y, xv, a1);
        a2 = fmaf(w.z, xv, a2);
        a3 = fmaf(w.w, xv, a3);
    }
    {
        float4 acc = make_float4(a0, a1, a2, a3);
        *(float4*)&part[kh][n][c4 * 4] = acc;
    }
    __syncthreads();

    // ---- reduce 8 partials + bias ----
    if (tid < 512) {
        int n2 = tid >> 6;
        int cl = tid & 63;
        int g2 = cl >> 4;
        int jj = cl & 15;
        float s = b[g2 * HH + j0 + jj];
        #pragma unroll
        for (int k2 = 0; k2 < 8; ++k2) s += part[k2][n2][cl];
        As[n2][cl] = s;
    }
    __syncthreads();

    // ---- gates: 128 cells (8 rows x 16 j) ----
    if (tid < 128) {
        int nn = tid >> 4;
        int q  = tid & 15;
        float Ai = As[nn][q];
        float Af = As[nn][16 + q];
        float Ao = As[nn][32 + q];
        float Ag = As[nn][48 + q];

        int gn = n0 + nn;
        int gj = j0 + q;

        float c_old = (t == 0) ? 0.0f : c_state[gn * HH + gj];

        float ig = 1.0f / (1.0f + __expf(-Ai));
        float fg = 1.0f / (1.0f + __expf(-Af));
        float og = 1.0f / (1.0f + __expf(-Ao));
        float gg = tanhf(Ag);

        float cn = fg * c_old + ig * gg;
        float hn = og * tanhf(cn);

        c_state[gn * HH + gj] = cn;
        out[((size_t)gn * TT + t) * HH + gj] = hn;
    }
}

extern "C" void kernel_launch(void* const* d_in, const int* in_sizes, int n_in,
                              void* d_out, int out_size, void* d_ws, size_t ws_size,
                              hipStream_t stream)
{
    const float* x  = (const float*)d_in[0];
    const float* h0 = (const float*)d_in[1];
    const float* Wx = (const float*)d_in[2];
    const float* Wh = (const float*)d_in[3];
    const float* b  = (const float*)d_in[4];
    float* out     = (float*)d_out;
    float* c_state = (float*)d_ws;   // 128 KB

    dim3 grid(32, 8);
    for (int t = 0; t < TT; ++t) {
        lstm_step<<<grid, 1024, 0, stream>>>(x, h0, Wx, Wh, b, out, c_state, t);
    }
}